// Round 9
// baseline (226.504 us; speedup 1.0000x reference)
//
#include <hip/hip_runtime.h>

#define BATCH 512
#define NPART 60
#define PFEAT 20
#define SFEAT 14
#define NVTX  5
#define HID   60
#define DE    20
#define DO    24
#define NCLS  2
#define HP    64          // padded hidden stride (fp16 rows)

#define SENDER_BLOCKS (BATCH*NPART/4)    // 7680
#define PV_BLOCKS     (BATCH*NVTX/4)     // 640
#define PREA_BLOCKS   (BATCH*NPART/256)  // 120 (64 rows/wave, 4 waves/block)
#define A2_BLOCKS     (BATCH/4)          // 128

typedef _Float16 half8  __attribute__((ext_vector_type(8)));
typedef _Float16 half4v __attribute__((ext_vector_type(4)));
typedef __fp16   fp16x2 __attribute__((ext_vector_type(2)));
typedef float    f32x4  __attribute__((ext_vector_type(4)));

__device__ __forceinline__ half4v pkcvt4(f32x4 a) {
    fp16x2 lo = __builtin_amdgcn_cvt_pkrtz(a[0], a[1]);
    fp16x2 hi = __builtin_amdgcn_cvt_pkrtz(a[2], a[3]);
    half4v r;
    r[0] = (_Float16)lo[0]; r[1] = (_Float16)lo[1];
    r[2] = (_Float16)hi[0]; r[3] = (_Float16)hi[1];
    return r;
}
__device__ __forceinline__ half4v relu4(half4v a) {
#pragma unroll
    for (int j = 0; j < 4; ++j)
        a[j] = (a[j] > (_Float16)0.f) ? a[j] : (_Float16)0.f;
    return a;
}
// Guarded per-lane float4 bias load: C-layout rows m = col4..col4+3.
__device__ __forceinline__ f32x4 bias4(const float* b, int col4, int lim) {
    f32x4 z = {0.f, 0.f, 0.f, 0.f};
    return (col4 < lim) ? *(const f32x4*)(b + col4) : z;
}

// ---------------------------------------------------------------------------
// TRANSPOSED formulation (A-frag lane map == B-frag lane map under m<->n):
// (a) B-layout weight tables ARE A-layout W^T tables; (b) a C-layout tile is
// directly a valid B-operand (k=row, n=col). Every layer:
// C[m=out_feat][n=item] = mfma(A=W-table, B=activation frags); layer-to-layer
// is just pkcvt+relu. No transpose MFMA, no LDS.
// ---------------------------------------------------------------------------

// ---------------------------------------------------------------------------
// Pack kernel — SEPARATE FIRST LAUNCH (round-7 topology; all consumers are in
// later launches; intra-launch block ordering is undefined).
// x32 table: lane L holds W[k=kk*32+(L>>4)*8+j][n=u*16+(L&15)]
// x16 table: lane L holds W[k=kt*16+(L>>4)*4+j][n=u*16+(L&15)]
// ---------------------------------------------------------------------------
__global__ __launch_bounds__(256) void pack_kernel(
    const float* __restrict__ fr_w2, const float* __restrict__ fr_w3,
    const float* __restrict__ pv_w2, const float* __restrict__ pv_w3,
    const float* __restrict__ fo_w1, const float* __restrict__ fo_w2,
    const float* __restrict__ fo_w3,
    _Float16* __restrict__ frW2p, _Float16* __restrict__ frW3p16,
    _Float16* __restrict__ pvW2p, _Float16* __restrict__ pvW3p16,
    _Float16* __restrict__ foW1p, _Float16* __restrict__ foW2p16,
    _Float16* __restrict__ foW3p16)
{
    for (int idx = threadIdx.x; idx < 4096; idx += 256) {   // x32, u<4, kk<2
        int j  = idx & 7;
        int L  = (idx >> 3) & 63;
        int kk = (idx >> 9) & 1;
        int u  = idx >> 10;
        int k  = kk*32 + (L >> 4)*8 + j;
        int n  = u*16 + (L & 15);
        bool ok = (k < HID && n < HID);
        frW2p[idx] = (_Float16)(ok ? fr_w2[k*HID + n] : 0.f);
        pvW2p[idx] = (_Float16)(ok ? pv_w2[k*HID + n] : 0.f);
        foW1p[idx] = (_Float16)(ok ? fo_w1[k*HID + n] : 0.f);
    }
    for (int idx = threadIdx.x; idx < 4096; idx += 256) {   // x16, u<4: fo_w2
        int j  = idx & 3;
        int L  = (idx >> 2) & 63;
        int kt = (idx >> 8) & 3;
        int u  = idx >> 10;
        int k  = kt*16 + (L >> 4)*4 + j;
        int n  = u*16 + (L & 15);
        foW2p16[idx] = (_Float16)((k < HID && n < HID) ? fo_w2[k*HID + n] : 0.f);
    }
    for (int idx = threadIdx.x; idx < 2048; idx += 256) {   // x16, u<2: w3 tables
        int j  = idx & 3;
        int L  = (idx >> 2) & 63;
        int kt = (idx >> 8) & 3;
        int u  = idx >> 10;
        int k  = kt*16 + (L >> 4)*4 + j;
        int n  = u*16 + (L & 15);
        frW3p16[idx] = (_Float16)((k < HID && n < DE) ? fr_w3[k*DE + n] : 0.f);
        pvW3p16[idx] = (_Float16)((k < HID && n < DE) ? pv_w3[k*DE + n] : 0.f);
        foW3p16[idx] = (_Float16)((k < HID && n < DO) ? fo_w3[k*DO + n] : 0.f);
    }
}

// ---------------------------------------------------------------------------
// Pre-kernel: two independent block ranges (write-sets disjoint, no
// intra-launch consumption).
//  [0, PREA_BLOCKS): stage A (MFMA, transposed): frA/frB/pvA; waves self-pack
//                    their W1 fragments from global (tiny, L1-resident).
//  [PREA, +A2): stage A2 scalar: pvV.
// ---------------------------------------------------------------------------
__global__ __launch_bounds__(256) void pre_kernel(
    const float* __restrict__ x, const float* __restrict__ y,
    const float* __restrict__ fr_w1, const float* __restrict__ fr_b1,
    const float* __restrict__ pv_w1, const float* __restrict__ pv_b1,
    _Float16* __restrict__ frA, _Float16* __restrict__ frB,
    _Float16* __restrict__ pvA, _Float16* __restrict__ pvV)
{
    int wave = threadIdx.x >> 6;
    int lane = threadIdx.x & 63;
    int ml   = lane & 15;
    int q    = lane >> 4;

    if (blockIdx.x < PREA_BLOCKS) {
        int wv = blockIdx.x*4 + wave;          // 0..479
        int rowBase = wv*64;
        // B-frags of x^T: lane holds x[bp = rowBase+16t+ml][k = q*8+j], k<20
        half8 bX[4];
#pragma unroll
        for (int t = 0; t < 4; ++t) {
            int bp = rowBase + 16*t + ml;
            int b = bp / NPART;
            int p = bp - b*NPART;
            const float* xb = x + (size_t)b*PFEAT*NPART + p;
            half8 v8;
#pragma unroll
            for (int j = 0; j < 8; ++j) {
                int k = q*8 + j;
                v8[j] = (_Float16)((k < PFEAT) ? xb[(size_t)k*NPART] : 0.f);
            }
            bX[t] = v8;
        }
#pragma unroll
        for (int mat = 0; mat < 3; ++mat) {
            const float* W = (mat == 0) ? fr_w1 : (mat == 1) ? (fr_w1 + PFEAT*HID) : pv_w1;
            _Float16*   Ot = (mat == 0) ? frA : (mat == 1) ? frB : pvA;
            // self-pack W1 A-frags (A-layout of W^T == B-layout of W)
            half8 aW[4];
#pragma unroll
            for (int u = 0; u < 4; ++u) {
                int n = u*16 + ml;
                half8 w8;
#pragma unroll
                for (int j = 0; j < 8; ++j) {
                    int k = q*8 + j;
                    w8[j] = (_Float16)((k < PFEAT && n < HID) ? W[k*HID + n] : 0.f);
                }
                aW[u] = w8;
            }
            f32x4 acc[4][4];
#pragma unroll
            for (int u = 0; u < 4; ++u) {
                f32x4 bi = (mat == 0) ? bias4(fr_b1, u*16 + 4*q, HID - 3)
                                      : (f32x4){0.f, 0.f, 0.f, 0.f};
#pragma unroll
                for (int t = 0; t < 4; ++t) acc[u][t] = bi;
            }
#pragma unroll
            for (int u = 0; u < 4; ++u)
#pragma unroll
                for (int t = 0; t < 4; ++t)
                    acc[u][t] = __builtin_amdgcn_mfma_f32_16x16x32_f16(aW[u], bX[t], acc[u][t], 0, 0, 0);
            // C[m=h][n=bp] -> contiguous half4 stores per lane
#pragma unroll
            for (int u = 0; u < 4; ++u)
#pragma unroll
                for (int t = 0; t < 4; ++t) {
                    half4v hv = pkcvt4(acc[u][t]);
                    int bp = rowBase + 16*t + ml;
                    *(half4v*)(Ot + (size_t)bp*HP + u*16 + 4*q) = hv;
                }
        }
    } else {
        int b = (blockIdx.x - PREA_BLOCKS)*4 + wave;
        int h = lane;
#pragma unroll
        for (int v = 0; v < NVTX; ++v) {
            if (h >= HID) { pvV[(b*NVTX + v)*HP + h] = (_Float16)0.f; continue; }
            float acc = pv_b1[h];
#pragma unroll
            for (int f = 0; f < SFEAT; ++f)
                acc += y[(b*SFEAT + f)*NVTX + v] * pv_w1[(PFEAT + f)*HID + h];
            pvV[(b*NVTX + v)*HP + h] = (_Float16)acc;
        }
    }
}

// ---------------------------------------------------------------------------
// Edge MLP (layers 2+3), transposed, MFMA only, zero LDS. 4 waves/block.
// Blocks [0, SENDER_BLOCKS): fr edges, g=(b,r), row-sum -> Epp (f32)
// Blocks [SENDER_BLOCKS, +PV_BLOCKS): pv edges, g=(b,v) -> Epv2 (f16 rows)
// ---------------------------------------------------------------------------
__global__ __launch_bounds__(256) void edge_mfma_kernel(
    const _Float16* __restrict__ frA, const _Float16* __restrict__ frB,
    const _Float16* __restrict__ pvV, const _Float16* __restrict__ pvA,
    const half8*  __restrict__ frw2p, const half4v* __restrict__ frw3p16,
    const half8*  __restrict__ pvw2p, const half4v* __restrict__ pvw3p16,
    const float* __restrict__ fr_b2, const float* __restrict__ fr_b3,
    const float* __restrict__ pv_b2, const float* __restrict__ pv_b3,
    float* __restrict__ Epp, _Float16* __restrict__ Epv2)
{
    int wave = threadIdx.x >> 6;
    int lane = threadIdx.x & 63;
    int ml   = lane & 15;
    int q    = lane >> 4;

    bool sender = blockIdx.x < SENDER_BLOCKS;

    int g, b, rv, VALID;
    const _Float16 *uni, *var;
    const half8  *w2p;
    const half4v *w3p;
    const float *b2, *b3;
    if (sender) {
        g = blockIdx.x*4 + wave;
        b = g / NPART; rv = g - b*NPART; VALID = NPART - 1;
        uni = frA + (size_t)g*HP; var = frB + (size_t)b*NPART*HP;
        w2p = frw2p; w3p = frw3p16; b2 = fr_b2; b3 = fr_b3;
    } else {
        g = (blockIdx.x - SENDER_BLOCKS)*4 + wave;
        b = g / NVTX; rv = g - b*NVTX; VALID = NPART;
        uni = pvV + (size_t)g*HP; var = pvA + (size_t)b*NPART*HP;
        w2p = pvw2p; w3p = pvw3p16; b2 = pv_b2; b3 = pv_b3;
    }

    int srcRow[4];
#pragma unroll
    for (int t = 0; t < 4; ++t) {
        int row = 16*t + ml;
        int s;
        if (sender) s = (row < VALID) ? (row + (row >= rv)) : 0;
        else        s = (row < VALID) ? row : 0;
        srcRow[t] = s;
    }

    // ---- h1 frags (B-operand: k=feature, n=edge): h1 = relu(uni + var[srcRow]) ----
    half8 bA[4][2];
#pragma unroll
    for (int t = 0; t < 4; ++t) {
#pragma unroll
        for (int kk = 0; kk < 2; ++kk) {
            half8 u8 = *(const half8*)(uni + kk*32 + q*8);
            half8 v8 = *(const half8*)(var + (size_t)srcRow[t]*HP + kk*32 + q*8);
            half8 s8 = u8 + v8;
#pragma unroll
            for (int j = 0; j < 8; ++j) {
                _Float16 vj = s8[j];
                s8[j] = (vj > (_Float16)0.f) ? vj : (_Float16)0.f;
            }
            bA[t][kk] = s8;
        }
    }

    // ---- layer 2: C2[m=f2][n=edge], bias rows in C-init ----
    f32x4 acc2[4][4];
#pragma unroll
    for (int u = 0; u < 4; ++u) {
        f32x4 bi = bias4(b2, u*16 + 4*q, HID - 3);
#pragma unroll
        for (int t = 0; t < 4; ++t) acc2[u][t] = bi;
    }
#pragma unroll
    for (int u = 0; u < 4; ++u) {
        half8 w0 = w2p[(u*2 + 0)*64 + lane];
        half8 w1 = w2p[(u*2 + 1)*64 + lane];
#pragma unroll
        for (int t = 0; t < 4; ++t) {
            acc2[u][t] = __builtin_amdgcn_mfma_f32_16x16x32_f16(w0, bA[t][0], acc2[u][t], 0, 0, 0);
            acc2[u][t] = __builtin_amdgcn_mfma_f32_16x16x32_f16(w1, bA[t][1], acc2[u][t], 0, 0, 0);
        }
    }

    // ---- cvt+relu: C-tiles directly become B-operands (k=f2, n=edge) ----
    half4v a3[4][4];
#pragma unroll
    for (int u = 0; u < 4; ++u)
#pragma unroll
        for (int t = 0; t < 4; ++t)
            a3[u][t] = relu4(pkcvt4(acc2[u][t]));

    // ---- layer 3: C3[m=e-feature][n=edge] ----
    f32x4 acc3[2][4];
#pragma unroll
    for (int v = 0; v < 2; ++v) {
        f32x4 bi = bias4(b3, v*16 + 4*q, DE - 3);
#pragma unroll
        for (int t = 0; t < 4; ++t) acc3[v][t] = bi;
    }
#pragma unroll
    for (int v = 0; v < 2; ++v)
#pragma unroll
        for (int u = 0; u < 4; ++u) {
            half4v w = w3p[(v*4 + u)*64 + lane];
#pragma unroll
            for (int t = 0; t < 4; ++t)
                acc3[v][t] = __builtin_amdgcn_mfma_f32_16x16x16f16(w, a3[u][t], acc3[v][t], 0, 0, 0);
        }

    if (sender) {
        // sum over edges (n): in-lane over t, butterfly over ml lanes
#pragma unroll
        for (int v = 0; v < 2; ++v) {
            float s[4] = {0.f, 0.f, 0.f, 0.f};
#pragma unroll
            for (int t = 0; t < 4; ++t) {
                int edge = 16*t + ml;
                bool ok = edge < VALID;
#pragma unroll
                for (int i = 0; i < 4; ++i) {
                    float val = fmaxf(acc3[v][t][i], 0.f);
                    s[i] += ok ? val : 0.f;
                }
            }
#pragma unroll
            for (int i = 0; i < 4; ++i) {
                s[i] += __shfl_xor(s[i], 1);
                s[i] += __shfl_xor(s[i], 2);
                s[i] += __shfl_xor(s[i], 4);
                s[i] += __shfl_xor(s[i], 8);
            }
            int col4 = v*16 + 4*q;
            if (ml == 0 && col4 < DE) {
                f32x4 o = {s[0], s[1], s[2], s[3]};
                *(f32x4*)(Epp + (size_t)g*DE + col4) = o;
            }
        }
    } else {
        // per-edge rows: contiguous half4 stores [edge][feat]
#pragma unroll
        for (int v = 0; v < 2; ++v) {
            int col4 = v*16 + 4*q;
#pragma unroll
            for (int t = 0; t < 4; ++t) {
                int edge = 16*t + ml;
                if (edge < VALID && col4 < DE) {
                    half4v hv = relu4(pkcvt4(acc3[v][t]));
                    *(half4v*)(Epv2 + ((size_t)g*64 + edge)*DE + col4) = hv;
                }
            }
        }
    }
}

// ---------------------------------------------------------------------------
// Prep (round-7 verbatim): cin[b*NPART+p][64] = fp16 [ x | Epp | sum_v Epv | 0 ]
// ---------------------------------------------------------------------------
__global__ __launch_bounds__(256) void prep_kernel(
    const float* __restrict__ x, const float* __restrict__ Epp,
    const _Float16* __restrict__ Epv2, _Float16* __restrict__ cin)
{
    int idx = blockIdx.x*256 + threadIdx.x;   // BATCH*NPART*64 total
    int bp = idx >> 6;
    int k  = idx & 63;
    int b  = bp / NPART;
    int p  = bp - b*NPART;

    float v;
    if (k < PFEAT) {
        v = x[(b*PFEAT + k)*NPART + p];
    } else if (k < PFEAT + DE) {
        v = Epp[(size_t)bp*DE + (k - PFEAT)];
    } else if (k < PFEAT + 2*DE) {
        int c = k - PFEAT - DE;
        float s = 0.f;
#pragma unroll
        for (int vv = 0; vv < NVTX; ++vv)
            s += (float)Epv2[(((size_t)b*NVTX + vv)*64 + p)*DE + c];
        v = s;
    } else {
        v = 0.f;
    }
    cin[(size_t)bp*HP + k] = (_Float16)v;
}

// ---------------------------------------------------------------------------
// Stage D: object MLP (transposed MFMA, zero LDS) + particle sum + fc head.
// 4 waves/block, one batch item per wave; B-frags straight from cin.
// ---------------------------------------------------------------------------
__global__ __launch_bounds__(256) void stageD_kernel(
    const _Float16* __restrict__ cin,
    const half8*  __restrict__ w1p, const half4v* __restrict__ w2p16,
    const half4v* __restrict__ w3p16,
    const float* __restrict__ b1, const float* __restrict__ b2,
    const float* __restrict__ b3,
    const float* __restrict__ fcw, const float* __restrict__ fcb,
    float* __restrict__ out)
{
    int wave = threadIdx.x >> 6;
    int lane = threadIdx.x & 63;
    int ml   = lane & 15;
    int q    = lane >> 4;
    int b    = blockIdx.x*4 + wave;

    const _Float16* base = cin + (size_t)b * NPART * HP;

    // ---- cin B-frags: k=feature, n=particle (clamp pad rows; masked later) ----
    half8 bC[4][2];
#pragma unroll
    for (int t = 0; t < 4; ++t) {
        int p = 16*t + ml;
        int sp = (p < NPART) ? p : 0;
#pragma unroll
        for (int kk = 0; kk < 2; ++kk)
            bC[t][kk] = *(const half8*)(base + (size_t)sp*HP + kk*32 + q*8);
    }

    // ---- layer 1 (x32): C[m=f1][n=particle] ----
    f32x4 acc1[4][4];
#pragma unroll
    for (int u = 0; u < 4; ++u) {
        f32x4 bi = bias4(b1, u*16 + 4*q, HID - 3);
#pragma unroll
        for (int t = 0; t < 4; ++t) acc1[u][t] = bi;
    }
#pragma unroll
    for (int u = 0; u < 4; ++u) {
        half8 w0 = w1p[(u*2 + 0)*64 + lane];
        half8 w1 = w1p[(u*2 + 1)*64 + lane];
#pragma unroll
        for (int t = 0; t < 4; ++t) {
            acc1[u][t] = __builtin_amdgcn_mfma_f32_16x16x32_f16(w0, bC[t][0], acc1[u][t], 0, 0, 0);
            acc1[u][t] = __builtin_amdgcn_mfma_f32_16x16x32_f16(w1, bC[t][1], acc1[u][t], 0, 0, 0);
        }
    }
    half4v a2[4][4];
#pragma unroll
    for (int u = 0; u < 4; ++u)
#pragma unroll
        for (int t = 0; t < 4; ++t)
            a2[u][t] = relu4(pkcvt4(acc1[u][t]));

    // ---- layer 2 (x16) ----
    f32x4 acc2[4][4];
#pragma unroll
    for (int u = 0; u < 4; ++u) {
        f32x4 bi = bias4(b2, u*16 + 4*q, HID - 3);
#pragma unroll
        for (int t = 0; t < 4; ++t) acc2[u][t] = bi;
    }
#pragma unroll
    for (int u = 0; u < 4; ++u)
#pragma unroll
        for (int kt = 0; kt < 4; ++kt) {
            half4v w = w2p16[(u*4 + kt)*64 + lane];
#pragma unroll
            for (int t = 0; t < 4; ++t)
                acc2[u][t] = __builtin_amdgcn_mfma_f32_16x16x16f16(w, a2[kt][t], acc2[u][t], 0, 0, 0);
        }
    half4v a3[4][4];
#pragma unroll
    for (int u = 0; u < 4; ++u)
#pragma unroll
        for (int t = 0; t < 4; ++t)
            a3[u][t] = relu4(pkcvt4(acc2[u][t]));

    // ---- layer 3 (x16): C[m=o-feature][n=particle] ----
    f32x4 acc3[2][4];
#pragma unroll
    for (int v = 0; v < 2; ++v) {
        f32x4 bi = bias4(b3, v*16 + 4*q, DO - 3);
#pragma unroll
        for (int t = 0; t < 4; ++t) acc3[v][t] = bi;
    }
#pragma unroll
    for (int v = 0; v < 2; ++v)
#pragma unroll
        for (int u = 0; u < 4; ++u) {
            half4v w = w3p16[(v*4 + u)*64 + lane];
#pragma unroll
            for (int t = 0; t < 4; ++t)
                acc3[v][t] = __builtin_amdgcn_mfma_f32_16x16x16f16(w, a3[u][t], acc3[v][t], 0, 0, 0);
        }

    // ---- epilogue: relu, sum over particles, fc head ----
    float s[2][4];
#pragma unroll
    for (int v = 0; v < 2; ++v) {
#pragma unroll
        for (int i = 0; i < 4; ++i) s[v][i] = 0.f;
#pragma unroll
        for (int t = 0; t < 4; ++t) {
            int p = 16*t + ml;
            bool ok = p < NPART;
#pragma unroll
            for (int i = 0; i < 4; ++i) {
                float val = fmaxf(acc3[v][t][i], 0.f);
                s[v][i] += ok ? val : 0.f;
            }
        }
#pragma unroll
        for (int i = 0; i < 4; ++i) {
            s[v][i] += __shfl_xor(s[v][i], 1);
            s[v][i] += __shfl_xor(s[v][i], 2);
            s[v][i] += __shfl_xor(s[v][i], 4);
            s[v][i] += __shfl_xor(s[v][i], 8);
        }
    }
    float pc[NCLS];
#pragma unroll
    for (int c = 0; c < NCLS; ++c) {
        float acc = 0.f;
        if (ml == 0) {
#pragma unroll
            for (int v = 0; v < 2; ++v)
#pragma unroll
                for (int i = 0; i < 4; ++i) {
                    int col = v*16 + 4*q + i;
                    if (col < DO) acc += s[v][i] * fcw[col*NCLS + c];
                }
        }
        acc += __shfl_xor(acc, 16);
        acc += __shfl_xor(acc, 32);
        pc[c] = acc;
    }
    if (lane == 0) {
        out[b*NCLS + 0] = pc[0] + fcb[0];
        out[b*NCLS + 1] = pc[1] + fcb[1];
    }
}

// ---------------------------------------------------------------------------
extern "C" void kernel_launch(void* const* d_in, const int* in_sizes, int n_in,
                              void* d_out, int out_size, void* d_ws, size_t ws_size,
                              hipStream_t stream)
{
    const float* x     = (const float*)d_in[0];
    const float* y     = (const float*)d_in[1];
    const float* fr_w1 = (const float*)d_in[2];
    const float* fr_b1 = (const float*)d_in[3];
    const float* fr_w2 = (const float*)d_in[4];
    const float* fr_b2 = (const float*)d_in[5];
    const float* fr_w3 = (const float*)d_in[6];
    const float* fr_b3 = (const float*)d_in[7];
    const float* pv_w1 = (const float*)d_in[8];
    const float* pv_b1 = (const float*)d_in[9];
    const float* pv_w2 = (const float*)d_in[10];
    const float* pv_b2 = (const float*)d_in[11];
    const float* pv_w3 = (const float*)d_in[12];
    const float* pv_b3 = (const float*)d_in[13];
    const float* fo_w1 = (const float*)d_in[14];
    const float* fo_b1 = (const float*)d_in[15];
    const float* fo_w2 = (const float*)d_in[16];
    const float* fo_b2 = (const float*)d_in[17];
    const float* fo_w3 = (const float*)d_in[18];
    const float* fo_b3 = (const float*)d_in[19];
    const float* fc_w  = (const float*)d_in[20];
    const float* fc_b  = (const float*)d_in[21];
    float* out = (float*)d_out;

    char* wsb = (char*)d_ws;
    size_t off = 0;
    auto alloc = [&](size_t bytes) { char* p = wsb + off; off += (bytes + 255) & ~(size_t)255; return p; };

    _Float16* frA  = (_Float16*)alloc((size_t)BATCH*NPART*HP*2);
    _Float16* frB  = (_Float16*)alloc((size_t)BATCH*NPART*HP*2);
    _Float16* pvA  = (_Float16*)alloc((size_t)BATCH*NPART*HP*2);
    _Float16* pvV  = (_Float16*)alloc((size_t)BATCH*NVTX*HP*2);
    float*    Epp  = (float*)   alloc((size_t)BATCH*NPART*DE*4);
    _Float16* Epv2 = (_Float16*)alloc((size_t)BATCH*NVTX*64*DE*2);
    _Float16* cin  = (_Float16*)alloc((size_t)BATCH*NPART*HP*2);
    _Float16* frW2p   = (_Float16*)alloc(4096*2);
    _Float16* frW3p16 = (_Float16*)alloc(2048*2);
    _Float16* pvW2p   = (_Float16*)alloc(4096*2);
    _Float16* pvW3p16 = (_Float16*)alloc(2048*2);
    _Float16* foW1p   = (_Float16*)alloc(4096*2);
    _Float16* foW2p16 = (_Float16*)alloc(4096*2);
    _Float16* foW3p16 = (_Float16*)alloc(2048*2);

    pack_kernel<<<1, 256, 0, stream>>>(
        fr_w2, fr_w3, pv_w2, pv_w3, fo_w1, fo_w2, fo_w3,
        frW2p, frW3p16, pvW2p, pvW3p16, foW1p, foW2p16, foW3p16);

    pre_kernel<<<PREA_BLOCKS + A2_BLOCKS, 256, 0, stream>>>(
        x, y, fr_w1, fr_b1, pv_w1, pv_b1,
        frA, frB, pvA, pvV);

    edge_mfma_kernel<<<SENDER_BLOCKS + PV_BLOCKS, 256, 0, stream>>>(
        frA, frB, pvV, pvA,
        (const half8*)frW2p, (const half4v*)frW3p16,
        (const half8*)pvW2p, (const half4v*)pvW3p16,
        fr_b2, fr_b3, pv_b2, pv_b3, Epp, Epv2);

    prep_kernel<<<(BATCH*NPART*HP)/256, 256, 0, stream>>>(x, Epp, Epv2, cin);

    stageD_kernel<<<BATCH/4, 256, 0, stream>>>(cin,
        (const half8*)foW1p, (const half4v*)foW2p16, (const half4v*)foW3p16,
        fo_b1, fo_b2, fo_b3, fc_w, fc_b, out);
}

// Round 10
// 208.499 us; speedup vs baseline: 1.0864x; 1.0864x over previous
//
#include <hip/hip_runtime.h>

#define BATCH 512
#define NPART 60
#define PFEAT 20
#define SFEAT 14
#define NVTX  5
#define HID   60
#define DE    20
#define DO    24
#define NCLS  2
#define SR    68          // LDS row stride in halves: stride 34 words -> 2-way banks max

typedef _Float16 half8  __attribute__((ext_vector_type(8)));
typedef _Float16 half4v __attribute__((ext_vector_type(4)));
typedef __fp16   fp16x2 __attribute__((ext_vector_type(2)));
typedef float    f32x4  __attribute__((ext_vector_type(4)));

__device__ __forceinline__ half4v pkcvt4(f32x4 a) {
    fp16x2 lo = __builtin_amdgcn_cvt_pkrtz(a[0], a[1]);
    fp16x2 hi = __builtin_amdgcn_cvt_pkrtz(a[2], a[3]);
    half4v r;
    r[0] = (_Float16)lo[0]; r[1] = (_Float16)lo[1];
    r[2] = (_Float16)hi[0]; r[3] = (_Float16)hi[1];
    return r;
}
__device__ __forceinline__ half4v relu4(half4v a) {
#pragma unroll
    for (int j = 0; j < 4; ++j)
        a[j] = (a[j] > (_Float16)0.f) ? a[j] : (_Float16)0.f;
    return a;
}
__device__ __forceinline__ f32x4 bias4(const float* b, int col4, int lim) {
    f32x4 z = {0.f, 0.f, 0.f, 0.f};
    return (col4 < lim) ? *(const f32x4*)(b + col4) : z;
}

// ---------------------------------------------------------------------------
// Pack kernel — separate first launch (consumers in the NEXT launch only).
// x32 table: lane L holds W[k=kk*32+(L>>4)*8+j][n=u*16+(L&15)]
// x16 table: lane L holds W[k=kt*16+(L>>4)*4+j][n=u*16+(L&15)]
// (B-layout of W == A-layout of W^T; used as A operands in transposed form.)
// ---------------------------------------------------------------------------
__global__ __launch_bounds__(256) void pack_kernel(
    const float* __restrict__ fr_w2, const float* __restrict__ fr_w3,
    const float* __restrict__ pv_w2, const float* __restrict__ pv_w3,
    const float* __restrict__ fo_w1, const float* __restrict__ fo_w2,
    const float* __restrict__ fo_w3,
    _Float16* __restrict__ frW2p, _Float16* __restrict__ frW3p16,
    _Float16* __restrict__ pvW2p, _Float16* __restrict__ pvW3p16,
    _Float16* __restrict__ foW1p, _Float16* __restrict__ foW2p16,
    _Float16* __restrict__ foW3p16)
{
    for (int idx = threadIdx.x; idx < 4096; idx += 256) {   // x32, u<4, kk<2
        int j  = idx & 7;
        int L  = (idx >> 3) & 63;
        int kk = (idx >> 9) & 1;
        int u  = idx >> 10;
        int k  = kk*32 + (L >> 4)*8 + j;
        int n  = u*16 + (L & 15);
        bool ok = (k < HID && n < HID);
        frW2p[idx] = (_Float16)(ok ? fr_w2[k*HID + n] : 0.f);
        pvW2p[idx] = (_Float16)(ok ? pv_w2[k*HID + n] : 0.f);
        foW1p[idx] = (_Float16)(ok ? fo_w1[k*HID + n] : 0.f);
    }
    for (int idx = threadIdx.x; idx < 4096; idx += 256) {   // x16, u<4: fo_w2
        int j  = idx & 3;
        int L  = (idx >> 2) & 63;
        int kt = (idx >> 8) & 3;
        int u  = idx >> 10;
        int k  = kt*16 + (L >> 4)*4 + j;
        int n  = u*16 + (L & 15);
        foW2p16[idx] = (_Float16)((k < HID && n < HID) ? fo_w2[k*HID + n] : 0.f);
    }
    for (int idx = threadIdx.x; idx < 2048; idx += 256) {   // x16, u<2: w3 tables
        int j  = idx & 3;
        int L  = (idx >> 2) & 63;
        int kt = (idx >> 8) & 3;
        int u  = idx >> 10;
        int k  = kt*16 + (L >> 4)*4 + j;
        int n  = u*16 + (L & 15);
        frW3p16[idx] = (_Float16)((k < HID && n < DE) ? fr_w3[k*DE + n] : 0.f);
        pvW3p16[idx] = (_Float16)((k < HID && n < DE) ? pv_w3[k*DE + n] : 0.f);
        foW3p16[idx] = (_Float16)((k < HID && n < DO) ? fo_w3[k*DO + n] : 0.f);
    }
}

// ---------------------------------------------------------------------------
// Fused network kernel: one block per batch item, 4 waves. Phases separated by
// __syncthreads:
//  P0: stage A (layer-1 partials, MFMA transposed) -> sFrA/sFrB/sPvA; pvV loop.
//  P1: fr-edge groups (15/wave, weights in regs) -> sEpp; pv groups -> sEpvP.
//  P2: cin gather -> sCin (aliases sFrA; frA dead after P1).
//  P3: object MLP per wave-tile -> sDsum partials; wave 0 does fc head.
// ---------------------------------------------------------------------------
__global__ __launch_bounds__(256) void fused_kernel(
    const float* __restrict__ x, const float* __restrict__ y,
    const float* __restrict__ fr_w1, const float* __restrict__ fr_b1,
    const float* __restrict__ fr_b2, const float* __restrict__ fr_b3,
    const float* __restrict__ pv_w1, const float* __restrict__ pv_b1,
    const float* __restrict__ pv_b2, const float* __restrict__ pv_b3,
    const float* __restrict__ fo_b1, const float* __restrict__ fo_b2,
    const float* __restrict__ fo_b3,
    const float* __restrict__ fcw, const float* __restrict__ fcb,
    const half8*  __restrict__ frw2p, const half4v* __restrict__ frw3p16,
    const half8*  __restrict__ pvw2p, const half4v* __restrict__ pvw3p16,
    const half8*  __restrict__ fow1p, const half4v* __restrict__ fow2p16,
    const half4v* __restrict__ fow3p16,
    float* __restrict__ out)
{
    __shared__ __align__(16) _Float16 sFrA[NPART*SR];   // P2+: aliased as sCin
    __shared__ __align__(16) _Float16 sFrB[NPART*SR];
    __shared__ __align__(16) _Float16 sPvA[NPART*SR];
    __shared__ __align__(16) _Float16 sPvV[NVTX*64];
    __shared__ __align__(16) float    sEpp[NPART*DE];
    __shared__ __align__(16) _Float16 sEpvP[4][NPART*DE];
    __shared__ __align__(16) float    sDsum[4][DO];
    _Float16* sCin = sFrA;

    int bb   = blockIdx.x;
    int wv   = threadIdx.x >> 6;
    int lane = threadIdx.x & 63;
    int ml   = lane & 15;
    int q    = lane >> 4;

    // ================= P0: stage A (wave wv owns row tile t=wv) =============
    {
        int row = 16*wv + ml;
        int rr  = (row < NPART) ? row : 0;
        const float* xb = x + (size_t)bb*PFEAT*NPART;
        half8 bX;
#pragma unroll
        for (int j = 0; j < 8; ++j) {
            int k = q*8 + j;
            bX[j] = (_Float16)((k < PFEAT) ? xb[(size_t)k*NPART + rr] : 0.f);
        }
#pragma unroll
        for (int mat = 0; mat < 3; ++mat) {
            const float* W = (mat == 0) ? fr_w1 : (mat == 1) ? (fr_w1 + PFEAT*HID) : pv_w1;
            _Float16*   Ot = (mat == 0) ? sFrA : (mat == 1) ? sFrB : sPvA;
            f32x4 acc[4];
#pragma unroll
            for (int u = 0; u < 4; ++u) {
                int n = u*16 + ml;
                half8 w8;
#pragma unroll
                for (int j = 0; j < 8; ++j) {
                    int k = q*8 + j;
                    w8[j] = (_Float16)((k < PFEAT && n < HID) ? W[k*HID + n] : 0.f);
                }
                acc[u] = (mat == 0) ? bias4(fr_b1, u*16 + 4*q, HID - 3)
                                    : (f32x4){0.f, 0.f, 0.f, 0.f};
                acc[u] = __builtin_amdgcn_mfma_f32_16x16x32_f16(w8, bX, acc[u], 0, 0, 0);
            }
            if (row < NPART) {
#pragma unroll
                for (int u = 0; u < 4; ++u)
                    *(half4v*)(Ot + row*SR + u*16 + 4*q) = pkcvt4(acc[u]);
            }
        }
        // pvV: block-stride scalar loop (5*64 outputs)
        for (int idx = threadIdx.x; idx < NVTX*64; idx += 256) {
            int v = idx >> 6;
            int h = idx & 63;
            float a = 0.f;
            if (h < HID) {
                a = pv_b1[h];
#pragma unroll
                for (int f = 0; f < SFEAT; ++f)
                    a += y[((size_t)bb*SFEAT + f)*NVTX + v] * pv_w1[(PFEAT + f)*HID + h];
            }
            sPvV[idx] = (_Float16)a;
        }
    }
    __syncthreads();

    // ================= P1a: fr-edge groups (r = wv, wv+4, ...) ===============
    {
        half8  w2r0[4], w2r1[4];
        half4v w3r[8];
#pragma unroll
        for (int u = 0; u < 4; ++u) {
            w2r0[u] = frw2p[(u*2 + 0)*64 + lane];
            w2r1[u] = frw2p[(u*2 + 1)*64 + lane];
        }
#pragma unroll
        for (int z = 0; z < 8; ++z) w3r[z] = frw3p16[z*64 + lane];
        f32x4 b2i[4], b3i[2];
#pragma unroll
        for (int u = 0; u < 4; ++u) b2i[u] = bias4(fr_b2, u*16 + 4*q, HID - 3);
#pragma unroll
        for (int v = 0; v < 2; ++v) b3i[v] = bias4(fr_b3, v*16 + 4*q, DE - 3);

        for (int r = wv; r < NPART; r += 4) {
            half8 bA[4][2];
#pragma unroll
            for (int t = 0; t < 4; ++t) {
                int edge = 16*t + ml;
                int s = (edge < NPART-1) ? (edge + (edge >= r)) : 0;
#pragma unroll
                for (int kk = 0; kk < 2; ++kk) {
                    half8 u8 = *(const half8*)(sFrA + r*SR + kk*32 + q*8);
                    half8 v8 = *(const half8*)(sFrB + s*SR + kk*32 + q*8);
                    half8 s8 = u8 + v8;
#pragma unroll
                    for (int j = 0; j < 8; ++j) {
                        _Float16 vj = s8[j];
                        s8[j] = (vj > (_Float16)0.f) ? vj : (_Float16)0.f;
                    }
                    bA[t][kk] = s8;
                }
            }
            f32x4 acc2[4][4];
#pragma unroll
            for (int u = 0; u < 4; ++u)
#pragma unroll
                for (int t = 0; t < 4; ++t) acc2[u][t] = b2i[u];
#pragma unroll
            for (int u = 0; u < 4; ++u)
#pragma unroll
                for (int t = 0; t < 4; ++t) {
                    acc2[u][t] = __builtin_amdgcn_mfma_f32_16x16x32_f16(w2r0[u], bA[t][0], acc2[u][t], 0, 0, 0);
                    acc2[u][t] = __builtin_amdgcn_mfma_f32_16x16x32_f16(w2r1[u], bA[t][1], acc2[u][t], 0, 0, 0);
                }
            half4v a3[4][4];
#pragma unroll
            for (int u = 0; u < 4; ++u)
#pragma unroll
                for (int t = 0; t < 4; ++t)
                    a3[u][t] = relu4(pkcvt4(acc2[u][t]));
            f32x4 acc3[2][4];
#pragma unroll
            for (int v = 0; v < 2; ++v)
#pragma unroll
                for (int t = 0; t < 4; ++t) acc3[v][t] = b3i[v];
#pragma unroll
            for (int v = 0; v < 2; ++v)
#pragma unroll
                for (int u = 0; u < 4; ++u)
#pragma unroll
                    for (int t = 0; t < 4; ++t)
                        acc3[v][t] = __builtin_amdgcn_mfma_f32_16x16x16f16(w3r[v*4 + u], a3[u][t], acc3[v][t], 0, 0, 0);
            // sum over edges -> sEpp[r]
#pragma unroll
            for (int v = 0; v < 2; ++v) {
                float s[4] = {0.f, 0.f, 0.f, 0.f};
#pragma unroll
                for (int t = 0; t < 4; ++t) {
                    int edge = 16*t + ml;
                    bool ok = edge < NPART-1;
#pragma unroll
                    for (int i = 0; i < 4; ++i)
                        s[i] += ok ? fmaxf(acc3[v][t][i], 0.f) : 0.f;
                }
#pragma unroll
                for (int i = 0; i < 4; ++i) {
                    s[i] += __shfl_xor(s[i], 1);
                    s[i] += __shfl_xor(s[i], 2);
                    s[i] += __shfl_xor(s[i], 4);
                    s[i] += __shfl_xor(s[i], 8);
                }
                int col4 = v*16 + 4*q;
                if (ml == 0 && col4 < DE) {
                    f32x4 o = {s[0], s[1], s[2], s[3]};
                    *(f32x4*)(sEpp + r*DE + col4) = o;
                }
            }
        }

        // ============= P1b: pv-edge groups (gv = wv, wv+4) ==================
        half8  p2r0[4], p2r1[4];
        half4v p3r[8];
#pragma unroll
        for (int u = 0; u < 4; ++u) {
            p2r0[u] = pvw2p[(u*2 + 0)*64 + lane];
            p2r1[u] = pvw2p[(u*2 + 1)*64 + lane];
        }
#pragma unroll
        for (int z = 0; z < 8; ++z) p3r[z] = pvw3p16[z*64 + lane];
        f32x4 pb2[4], pb3[2];
#pragma unroll
        for (int u = 0; u < 4; ++u) pb2[u] = bias4(pv_b2, u*16 + 4*q, HID - 3);
#pragma unroll
        for (int v = 0; v < 2; ++v) pb3[v] = bias4(pv_b3, v*16 + 4*q, DE - 3);

        f32x4 sumPv[2][4];
#pragma unroll
        for (int v = 0; v < 2; ++v)
#pragma unroll
            for (int t = 0; t < 4; ++t) sumPv[v][t] = (f32x4){0.f, 0.f, 0.f, 0.f};

        for (int gv = wv; gv < NVTX; gv += 4) {
            half8 bA[4][2];
#pragma unroll
            for (int t = 0; t < 4; ++t) {
                int p = 16*t + ml;
                int s = (p < NPART) ? p : 0;
#pragma unroll
                for (int kk = 0; kk < 2; ++kk) {
                    half8 u8 = *(const half8*)(sPvV + gv*64 + kk*32 + q*8);
                    half8 v8 = *(const half8*)(sPvA + s*SR + kk*32 + q*8);
                    half8 s8 = u8 + v8;
#pragma unroll
                    for (int j = 0; j < 8; ++j) {
                        _Float16 vj = s8[j];
                        s8[j] = (vj > (_Float16)0.f) ? vj : (_Float16)0.f;
                    }
                    bA[t][kk] = s8;
                }
            }
            f32x4 acc2[4][4];
#pragma unroll
            for (int u = 0; u < 4; ++u)
#pragma unroll
                for (int t = 0; t < 4; ++t) acc2[u][t] = pb2[u];
#pragma unroll
            for (int u = 0; u < 4; ++u)
#pragma unroll
                for (int t = 0; t < 4; ++t) {
                    acc2[u][t] = __builtin_amdgcn_mfma_f32_16x16x32_f16(p2r0[u], bA[t][0], acc2[u][t], 0, 0, 0);
                    acc2[u][t] = __builtin_amdgcn_mfma_f32_16x16x32_f16(p2r1[u], bA[t][1], acc2[u][t], 0, 0, 0);
                }
            half4v a3[4][4];
#pragma unroll
            for (int u = 0; u < 4; ++u)
#pragma unroll
                for (int t = 0; t < 4; ++t)
                    a3[u][t] = relu4(pkcvt4(acc2[u][t]));
            f32x4 acc3[2][4];
#pragma unroll
            for (int v = 0; v < 2; ++v)
#pragma unroll
                for (int t = 0; t < 4; ++t) acc3[v][t] = pb3[v];
#pragma unroll
            for (int v = 0; v < 2; ++v)
#pragma unroll
                for (int u = 0; u < 4; ++u)
#pragma unroll
                    for (int t = 0; t < 4; ++t)
                        acc3[v][t] = __builtin_amdgcn_mfma_f32_16x16x16f16(p3r[v*4 + u], a3[u][t], acc3[v][t], 0, 0, 0);
#pragma unroll
            for (int v = 0; v < 2; ++v)
#pragma unroll
                for (int t = 0; t < 4; ++t)
#pragma unroll
                    for (int i = 0; i < 4; ++i)
                        sumPv[v][t][i] += fmaxf(acc3[v][t][i], 0.f);
        }
        // store per-wave pv partial sums: [particle][feat] f16
#pragma unroll
        for (int v = 0; v < 2; ++v) {
            int col4 = v*16 + 4*q;
#pragma unroll
            for (int t = 0; t < 4; ++t) {
                int p = 16*t + ml;
                if (p < NPART && col4 < DE)
                    *(half4v*)(sEpvP[wv] + p*DE + col4) = pkcvt4(sumPv[v][t]);
            }
        }
    }
    __syncthreads();

    // ================= P2: cin gather into sCin (aliases sFrA) ==============
    for (int idx = threadIdx.x; idx < NPART*64; idx += 256) {
        int p = idx >> 6;
        int k = idx & 63;
        float v;
        if (k < PFEAT) {
            v = x[((size_t)bb*PFEAT + k)*NPART + p];
        } else if (k < PFEAT + DE) {
            v = sEpp[p*DE + (k - PFEAT)];
        } else if (k < PFEAT + 2*DE) {
            int c = k - PFEAT - DE;
            float s = 0.f;
#pragma unroll
            for (int w4 = 0; w4 < 4; ++w4)
                s += (float)sEpvP[w4][p*DE + c];
            v = s;
        } else {
            v = 0.f;
        }
        sCin[p*SR + k] = (_Float16)v;
    }
    __syncthreads();

    // ================= P3: object MLP (wave wv owns particle tile t=wv) =====
    {
        half8 bC[2];
        int p = 16*wv + ml;
        int sp = (p < NPART) ? p : 0;
#pragma unroll
        for (int kk = 0; kk < 2; ++kk)
            bC[kk] = *(const half8*)(sCin + sp*SR + kk*32 + q*8);

        f32x4 acc1[4];
#pragma unroll
        for (int u = 0; u < 4; ++u) {
            acc1[u] = bias4(fo_b1, u*16 + 4*q, HID - 3);
            acc1[u] = __builtin_amdgcn_mfma_f32_16x16x32_f16(fow1p[(u*2 + 0)*64 + lane], bC[0], acc1[u], 0, 0, 0);
            acc1[u] = __builtin_amdgcn_mfma_f32_16x16x32_f16(fow1p[(u*2 + 1)*64 + lane], bC[1], acc1[u], 0, 0, 0);
        }
        half4v a2[4];
#pragma unroll
        for (int u = 0; u < 4; ++u) a2[u] = relu4(pkcvt4(acc1[u]));

        f32x4 acc2[4];
#pragma unroll
        for (int u = 0; u < 4; ++u) {
            acc2[u] = bias4(fo_b2, u*16 + 4*q, HID - 3);
#pragma unroll
            for (int kt = 0; kt < 4; ++kt)
                acc2[u] = __builtin_amdgcn_mfma_f32_16x16x16f16(fow2p16[(u*4 + kt)*64 + lane], a2[kt], acc2[u], 0, 0, 0);
        }
        half4v a3[4];
#pragma unroll
        for (int u = 0; u < 4; ++u) a3[u] = relu4(pkcvt4(acc2[u]));

        f32x4 acc3[2];
#pragma unroll
        for (int v = 0; v < 2; ++v) {
            acc3[v] = bias4(fo_b3, v*16 + 4*q, DO - 3);
#pragma unroll
            for (int u = 0; u < 4; ++u)
                acc3[v] = __builtin_amdgcn_mfma_f32_16x16x16f16(fow3p16[(v*4 + u)*64 + lane], a3[u], acc3[v], 0, 0, 0);
        }
        // per-wave particle partial (16 particles of this tile)
#pragma unroll
        for (int v = 0; v < 2; ++v) {
            float s[4];
            bool ok = p < NPART;
#pragma unroll
            for (int i = 0; i < 4; ++i)
                s[i] = ok ? fmaxf(acc3[v][i], 0.f) : 0.f;
#pragma unroll
            for (int i = 0; i < 4; ++i) {
                s[i] += __shfl_xor(s[i], 1);
                s[i] += __shfl_xor(s[i], 2);
                s[i] += __shfl_xor(s[i], 4);
                s[i] += __shfl_xor(s[i], 8);
            }
            int col4 = v*16 + 4*q;
            if (ml == 0 && col4 < DO) {
                f32x4 o = {s[0], s[1], s[2], s[3]};
                *(f32x4*)(sDsum[wv] + col4) = o;
            }
        }
    }
    __syncthreads();

    // ================= fc head (wave 0) =====================================
    if (wv == 0) {
        float tot = 0.f;
        if (lane < DO) {
#pragma unroll
            for (int w4 = 0; w4 < 4; ++w4) tot += sDsum[w4][lane];
        }
        float p0 = (lane < DO) ? tot * fcw[lane*NCLS + 0] : 0.f;
        float p1 = (lane < DO) ? tot * fcw[lane*NCLS + 1] : 0.f;
#pragma unroll
        for (int d = 1; d <= 16; d <<= 1) {
            p0 += __shfl_xor(p0, d);
            p1 += __shfl_xor(p1, d);
        }
        if (lane == 0) {
            out[bb*NCLS + 0] = p0 + fcb[0];
            out[bb*NCLS + 1] = p1 + fcb[1];
        }
    }
}

// ---------------------------------------------------------------------------
extern "C" void kernel_launch(void* const* d_in, const int* in_sizes, int n_in,
                              void* d_out, int out_size, void* d_ws, size_t ws_size,
                              hipStream_t stream)
{
    const float* x     = (const float*)d_in[0];
    const float* y     = (const float*)d_in[1];
    const float* fr_w1 = (const float*)d_in[2];
    const float* fr_b1 = (const float*)d_in[3];
    const float* fr_w2 = (const float*)d_in[4];
    const float* fr_b2 = (const float*)d_in[5];
    const float* fr_w3 = (const float*)d_in[6];
    const float* fr_b3 = (const float*)d_in[7];
    const float* pv_w1 = (const float*)d_in[8];
    const float* pv_b1 = (const float*)d_in[9];
    const float* pv_w2 = (const float*)d_in[10];
    const float* pv_b2 = (const float*)d_in[11];
    const float* pv_w3 = (const float*)d_in[12];
    const float* pv_b3 = (const float*)d_in[13];
    const float* fo_w1 = (const float*)d_in[14];
    const float* fo_b1 = (const float*)d_in[15];
    const float* fo_w2 = (const float*)d_in[16];
    const float* fo_b2 = (const float*)d_in[17];
    const float* fo_w3 = (const float*)d_in[18];
    const float* fo_b3 = (const float*)d_in[19];
    const float* fc_w  = (const float*)d_in[20];
    const float* fc_b  = (const float*)d_in[21];
    float* out = (float*)d_out;

    char* wsb = (char*)d_ws;
    size_t off = 0;
    auto alloc = [&](size_t bytes) { char* p = wsb + off; off += (bytes + 255) & ~(size_t)255; return p; };

    _Float16* frW2p   = (_Float16*)alloc(4096*2);
    _Float16* frW3p16 = (_Float16*)alloc(2048*2);
    _Float16* pvW2p   = (_Float16*)alloc(4096*2);
    _Float16* pvW3p16 = (_Float16*)alloc(2048*2);
    _Float16* foW1p   = (_Float16*)alloc(4096*2);
    _Float16* foW2p16 = (_Float16*)alloc(4096*2);
    _Float16* foW3p16 = (_Float16*)alloc(2048*2);

    pack_kernel<<<1, 256, 0, stream>>>(
        fr_w2, fr_w3, pv_w2, pv_w3, fo_w1, fo_w2, fo_w3,
        frW2p, frW3p16, pvW2p, pvW3p16, foW1p, foW2p16, foW3p16);

    fused_kernel<<<BATCH, 256, 0, stream>>>(
        x, y, fr_w1, fr_b1, fr_b2, fr_b3,
        pv_w1, pv_b1, pv_b2, pv_b3,
        fo_b1, fo_b2, fo_b3, fc_w, fc_b,
        (const half8*)frW2p, (const half4v*)frW3p16,
        (const half8*)pvW2p, (const half4v*)pvW3p16,
        (const half8*)foW1p, (const half4v*)foW2p16, (const half4v*)foW3p16,
        out);
}

// Round 11
// 187.260 us; speedup vs baseline: 1.2096x; 1.1134x over previous
//
#include <hip/hip_runtime.h>

#define BATCH 512
#define NPART 60
#define PFEAT 20
#define SFEAT 14
#define NVTX  5
#define HID   60
#define DE    20
#define DO    24
#define NCLS  2
#define SR    68          // LDS row stride in halves: stride 34 words -> 2-way banks max

typedef _Float16 half8  __attribute__((ext_vector_type(8)));
typedef _Float16 half4v __attribute__((ext_vector_type(4)));
typedef __fp16   fp16x2 __attribute__((ext_vector_type(2)));
typedef float    f32x4  __attribute__((ext_vector_type(4)));

__device__ __forceinline__ half4v pkcvt4(f32x4 a) {
    fp16x2 lo = __builtin_amdgcn_cvt_pkrtz(a[0], a[1]);
    fp16x2 hi = __builtin_amdgcn_cvt_pkrtz(a[2], a[3]);
    half4v r;
    r[0] = (_Float16)lo[0]; r[1] = (_Float16)lo[1];
    r[2] = (_Float16)hi[0]; r[3] = (_Float16)hi[1];
    return r;
}
__device__ __forceinline__ half4v relu4(half4v a) {
#pragma unroll
    for (int j = 0; j < 4; ++j)
        a[j] = (a[j] > (_Float16)0.f) ? a[j] : (_Float16)0.f;
    return a;
}
__device__ __forceinline__ f32x4 bias4(const float* b, int col4, int lim) {
    f32x4 z = {0.f, 0.f, 0.f, 0.f};
    return (col4 < lim) ? *(const f32x4*)(b + col4) : z;
}

// ---------------------------------------------------------------------------
// Pack kernel — PARALLELIZED: 16 blocks, one element per thread, no loops.
// (Round-10's single-block version was latency-serialized on one CU: ~88
// dependent scattered load->cvt->store chains x ~600-900 cyc cold-miss with
// only 4 waves to hide them ~= the ~100 us residual seen in every round's
// dispatch-sum accounting since round 2.)
// x32 table: lane L holds W[k=kk*32+(L>>4)*8+j][n=u*16+(L&15)]
// x16 table: lane L holds W[k=kt*16+(L>>4)*4+j][n=u*16+(L&15)]
// ---------------------------------------------------------------------------
__global__ __launch_bounds__(256) void pack_kernel(
    const float* __restrict__ fr_w2, const float* __restrict__ fr_w3,
    const float* __restrict__ pv_w2, const float* __restrict__ pv_w3,
    const float* __restrict__ fo_w1, const float* __restrict__ fo_w2,
    const float* __restrict__ fo_w3,
    _Float16* __restrict__ frW2p, _Float16* __restrict__ frW3p16,
    _Float16* __restrict__ pvW2p, _Float16* __restrict__ pvW3p16,
    _Float16* __restrict__ foW1p, _Float16* __restrict__ foW2p16,
    _Float16* __restrict__ foW3p16)
{
    int idx = blockIdx.x*256 + threadIdx.x;    // 0..4095 over 16 blocks
    {   // x32 tables, u<4, kk<2 (4096 elements)
        int j  = idx & 7;
        int L  = (idx >> 3) & 63;
        int kk = (idx >> 9) & 1;
        int u  = idx >> 10;
        int k  = kk*32 + (L >> 4)*8 + j;
        int n  = u*16 + (L & 15);
        bool ok = (k < HID && n < HID);
        frW2p[idx] = (_Float16)(ok ? fr_w2[k*HID + n] : 0.f);
        pvW2p[idx] = (_Float16)(ok ? pv_w2[k*HID + n] : 0.f);
        foW1p[idx] = (_Float16)(ok ? fo_w1[k*HID + n] : 0.f);
    }
    {   // x16 table, u<4: fo_w2 (4096 elements)
        int j  = idx & 3;
        int L  = (idx >> 2) & 63;
        int kt = (idx >> 8) & 3;
        int u  = idx >> 10;
        int k  = kt*16 + (L >> 4)*4 + j;
        int n  = u*16 + (L & 15);
        foW2p16[idx] = (_Float16)((k < HID && n < HID) ? fo_w2[k*HID + n] : 0.f);
    }
    if (idx < 2048) {   // x16 tables, u<2: w3 (2048 elements)
        int j  = idx & 3;
        int L  = (idx >> 2) & 63;
        int kt = (idx >> 8) & 3;
        int u  = idx >> 10;
        int k  = kt*16 + (L >> 4)*4 + j;
        int n  = u*16 + (L & 15);
        frW3p16[idx] = (_Float16)((k < HID && n < DE) ? fr_w3[k*DE + n] : 0.f);
        pvW3p16[idx] = (_Float16)((k < HID && n < DE) ? pv_w3[k*DE + n] : 0.f);
        foW3p16[idx] = (_Float16)((k < HID && n < DO) ? fo_w3[k*DO + n] : 0.f);
    }
}

// ---------------------------------------------------------------------------
// Fused network kernel (byte-identical to round 10): one block per batch item,
// 4 waves. Phases separated by __syncthreads:
//  P0: stage A (layer-1 partials, MFMA transposed) -> sFrA/sFrB/sPvA; pvV loop.
//  P1: fr-edge groups (15/wave, weights in regs) -> sEpp; pv groups -> sEpvP.
//  P2: cin gather -> sCin (aliases sFrA; frA dead after P1).
//  P3: object MLP per wave-tile -> sDsum partials; wave 0 does fc head.
// ---------------------------------------------------------------------------
__global__ __launch_bounds__(256) void fused_kernel(
    const float* __restrict__ x, const float* __restrict__ y,
    const float* __restrict__ fr_w1, const float* __restrict__ fr_b1,
    const float* __restrict__ fr_b2, const float* __restrict__ fr_b3,
    const float* __restrict__ pv_w1, const float* __restrict__ pv_b1,
    const float* __restrict__ pv_b2, const float* __restrict__ pv_b3,
    const float* __restrict__ fo_b1, const float* __restrict__ fo_b2,
    const float* __restrict__ fo_b3,
    const float* __restrict__ fcw, const float* __restrict__ fcb,
    const half8*  __restrict__ frw2p, const half4v* __restrict__ frw3p16,
    const half8*  __restrict__ pvw2p, const half4v* __restrict__ pvw3p16,
    const half8*  __restrict__ fow1p, const half4v* __restrict__ fow2p16,
    const half4v* __restrict__ fow3p16,
    float* __restrict__ out)
{
    __shared__ __align__(16) _Float16 sFrA[NPART*SR];   // P2+: aliased as sCin
    __shared__ __align__(16) _Float16 sFrB[NPART*SR];
    __shared__ __align__(16) _Float16 sPvA[NPART*SR];
    __shared__ __align__(16) _Float16 sPvV[NVTX*64];
    __shared__ __align__(16) float    sEpp[NPART*DE];
    __shared__ __align__(16) _Float16 sEpvP[4][NPART*DE];
    __shared__ __align__(16) float    sDsum[4][DO];
    _Float16* sCin = sFrA;

    int bb   = blockIdx.x;
    int wv   = threadIdx.x >> 6;
    int lane = threadIdx.x & 63;
    int ml   = lane & 15;
    int q    = lane >> 4;

    // ================= P0: stage A (wave wv owns row tile t=wv) =============
    {
        int row = 16*wv + ml;
        int rr  = (row < NPART) ? row : 0;
        const float* xb = x + (size_t)bb*PFEAT*NPART;
        half8 bX;
#pragma unroll
        for (int j = 0; j < 8; ++j) {
            int k = q*8 + j;
            bX[j] = (_Float16)((k < PFEAT) ? xb[(size_t)k*NPART + rr] : 0.f);
        }
#pragma unroll
        for (int mat = 0; mat < 3; ++mat) {
            const float* W = (mat == 0) ? fr_w1 : (mat == 1) ? (fr_w1 + PFEAT*HID) : pv_w1;
            _Float16*   Ot = (mat == 0) ? sFrA : (mat == 1) ? sFrB : sPvA;
            f32x4 acc[4];
#pragma unroll
            for (int u = 0; u < 4; ++u) {
                int n = u*16 + ml;
                half8 w8;
#pragma unroll
                for (int j = 0; j < 8; ++j) {
                    int k = q*8 + j;
                    w8[j] = (_Float16)((k < PFEAT && n < HID) ? W[k*HID + n] : 0.f);
                }
                acc[u] = (mat == 0) ? bias4(fr_b1, u*16 + 4*q, HID - 3)
                                    : (f32x4){0.f, 0.f, 0.f, 0.f};
                acc[u] = __builtin_amdgcn_mfma_f32_16x16x32_f16(w8, bX, acc[u], 0, 0, 0);
            }
            if (row < NPART) {
#pragma unroll
                for (int u = 0; u < 4; ++u)
                    *(half4v*)(Ot + row*SR + u*16 + 4*q) = pkcvt4(acc[u]);
            }
        }
        // pvV: block-stride scalar loop (5*64 outputs)
        for (int idx = threadIdx.x; idx < NVTX*64; idx += 256) {
            int v = idx >> 6;
            int h = idx & 63;
            float a = 0.f;
            if (h < HID) {
                a = pv_b1[h];
#pragma unroll
                for (int f = 0; f < SFEAT; ++f)
                    a += y[((size_t)bb*SFEAT + f)*NVTX + v] * pv_w1[(PFEAT + f)*HID + h];
            }
            sPvV[idx] = (_Float16)a;
        }
    }
    __syncthreads();

    // ================= P1a: fr-edge groups (r = wv, wv+4, ...) ===============
    {
        half8  w2r0[4], w2r1[4];
        half4v w3r[8];
#pragma unroll
        for (int u = 0; u < 4; ++u) {
            w2r0[u] = frw2p[(u*2 + 0)*64 + lane];
            w2r1[u] = frw2p[(u*2 + 1)*64 + lane];
        }
#pragma unroll
        for (int z = 0; z < 8; ++z) w3r[z] = frw3p16[z*64 + lane];
        f32x4 b2i[4], b3i[2];
#pragma unroll
        for (int u = 0; u < 4; ++u) b2i[u] = bias4(fr_b2, u*16 + 4*q, HID - 3);
#pragma unroll
        for (int v = 0; v < 2; ++v) b3i[v] = bias4(fr_b3, v*16 + 4*q, DE - 3);

        for (int r = wv; r < NPART; r += 4) {
            half8 bA[4][2];
#pragma unroll
            for (int t = 0; t < 4; ++t) {
                int edge = 16*t + ml;
                int s = (edge < NPART-1) ? (edge + (edge >= r)) : 0;
#pragma unroll
                for (int kk = 0; kk < 2; ++kk) {
                    half8 u8 = *(const half8*)(sFrA + r*SR + kk*32 + q*8);
                    half8 v8 = *(const half8*)(sFrB + s*SR + kk*32 + q*8);
                    half8 s8 = u8 + v8;
#pragma unroll
                    for (int j = 0; j < 8; ++j) {
                        _Float16 vj = s8[j];
                        s8[j] = (vj > (_Float16)0.f) ? vj : (_Float16)0.f;
                    }
                    bA[t][kk] = s8;
                }
            }
            f32x4 acc2[4][4];
#pragma unroll
            for (int u = 0; u < 4; ++u)
#pragma unroll
                for (int t = 0; t < 4; ++t) acc2[u][t] = b2i[u];
#pragma unroll
            for (int u = 0; u < 4; ++u)
#pragma unroll
                for (int t = 0; t < 4; ++t) {
                    acc2[u][t] = __builtin_amdgcn_mfma_f32_16x16x32_f16(w2r0[u], bA[t][0], acc2[u][t], 0, 0, 0);
                    acc2[u][t] = __builtin_amdgcn_mfma_f32_16x16x32_f16(w2r1[u], bA[t][1], acc2[u][t], 0, 0, 0);
                }
            half4v a3[4][4];
#pragma unroll
            for (int u = 0; u < 4; ++u)
#pragma unroll
                for (int t = 0; t < 4; ++t)
                    a3[u][t] = relu4(pkcvt4(acc2[u][t]));
            f32x4 acc3[2][4];
#pragma unroll
            for (int v = 0; v < 2; ++v)
#pragma unroll
                for (int t = 0; t < 4; ++t) acc3[v][t] = b3i[v];
#pragma unroll
            for (int v = 0; v < 2; ++v)
#pragma unroll
                for (int u = 0; u < 4; ++u)
#pragma unroll
                    for (int t = 0; t < 4; ++t)
                        acc3[v][t] = __builtin_amdgcn_mfma_f32_16x16x16f16(w3r[v*4 + u], a3[u][t], acc3[v][t], 0, 0, 0);
            // sum over edges -> sEpp[r]
#pragma unroll
            for (int v = 0; v < 2; ++v) {
                float s[4] = {0.f, 0.f, 0.f, 0.f};
#pragma unroll
                for (int t = 0; t < 4; ++t) {
                    int edge = 16*t + ml;
                    bool ok = edge < NPART-1;
#pragma unroll
                    for (int i = 0; i < 4; ++i)
                        s[i] += ok ? fmaxf(acc3[v][t][i], 0.f) : 0.f;
                }
#pragma unroll
                for (int i = 0; i < 4; ++i) {
                    s[i] += __shfl_xor(s[i], 1);
                    s[i] += __shfl_xor(s[i], 2);
                    s[i] += __shfl_xor(s[i], 4);
                    s[i] += __shfl_xor(s[i], 8);
                }
                int col4 = v*16 + 4*q;
                if (ml == 0 && col4 < DE) {
                    f32x4 o = {s[0], s[1], s[2], s[3]};
                    *(f32x4*)(sEpp + r*DE + col4) = o;
                }
            }
        }

        // ============= P1b: pv-edge groups (gv = wv, wv+4) ==================
        half8  p2r0[4], p2r1[4];
        half4v p3r[8];
#pragma unroll
        for (int u = 0; u < 4; ++u) {
            p2r0[u] = pvw2p[(u*2 + 0)*64 + lane];
            p2r1[u] = pvw2p[(u*2 + 1)*64 + lane];
        }
#pragma unroll
        for (int z = 0; z < 8; ++z) p3r[z] = pvw3p16[z*64 + lane];
        f32x4 pb2[4], pb3[2];
#pragma unroll
        for (int u = 0; u < 4; ++u) pb2[u] = bias4(pv_b2, u*16 + 4*q, HID - 3);
#pragma unroll
        for (int v = 0; v < 2; ++v) pb3[v] = bias4(pv_b3, v*16 + 4*q, DE - 3);

        f32x4 sumPv[2][4];
#pragma unroll
        for (int v = 0; v < 2; ++v)
#pragma unroll
            for (int t = 0; t < 4; ++t) sumPv[v][t] = (f32x4){0.f, 0.f, 0.f, 0.f};

        for (int gv = wv; gv < NVTX; gv += 4) {
            half8 bA[4][2];
#pragma unroll
            for (int t = 0; t < 4; ++t) {
                int p = 16*t + ml;
                int s = (p < NPART) ? p : 0;
#pragma unroll
                for (int kk = 0; kk < 2; ++kk) {
                    half8 u8 = *(const half8*)(sPvV + gv*64 + kk*32 + q*8);
                    half8 v8 = *(const half8*)(sPvA + s*SR + kk*32 + q*8);
                    half8 s8 = u8 + v8;
#pragma unroll
                    for (int j = 0; j < 8; ++j) {
                        _Float16 vj = s8[j];
                        s8[j] = (vj > (_Float16)0.f) ? vj : (_Float16)0.f;
                    }
                    bA[t][kk] = s8;
                }
            }
            f32x4 acc2[4][4];
#pragma unroll
            for (int u = 0; u < 4; ++u)
#pragma unroll
                for (int t = 0; t < 4; ++t) acc2[u][t] = pb2[u];
#pragma unroll
            for (int u = 0; u < 4; ++u)
#pragma unroll
                for (int t = 0; t < 4; ++t) {
                    acc2[u][t] = __builtin_amdgcn_mfma_f32_16x16x32_f16(p2r0[u], bA[t][0], acc2[u][t], 0, 0, 0);
                    acc2[u][t] = __builtin_amdgcn_mfma_f32_16x16x32_f16(p2r1[u], bA[t][1], acc2[u][t], 0, 0, 0);
                }
            half4v a3[4][4];
#pragma unroll
            for (int u = 0; u < 4; ++u)
#pragma unroll
                for (int t = 0; t < 4; ++t)
                    a3[u][t] = relu4(pkcvt4(acc2[u][t]));
            f32x4 acc3[2][4];
#pragma unroll
            for (int v = 0; v < 2; ++v)
#pragma unroll
                for (int t = 0; t < 4; ++t) acc3[v][t] = pb3[v];
#pragma unroll
            for (int v = 0; v < 2; ++v)
#pragma unroll
                for (int u = 0; u < 4; ++u)
#pragma unroll
                    for (int t = 0; t < 4; ++t)
                        acc3[v][t] = __builtin_amdgcn_mfma_f32_16x16x16f16(p3r[v*4 + u], a3[u][t], acc3[v][t], 0, 0, 0);
#pragma unroll
            for (int v = 0; v < 2; ++v)
#pragma unroll
                for (int t = 0; t < 4; ++t)
#pragma unroll
                    for (int i = 0; i < 4; ++i)
                        sumPv[v][t][i] += fmaxf(acc3[v][t][i], 0.f);
        }
        // store per-wave pv partial sums: [particle][feat] f16
#pragma unroll
        for (int v = 0; v < 2; ++v) {
            int col4 = v*16 + 4*q;
#pragma unroll
            for (int t = 0; t < 4; ++t) {
                int p = 16*t + ml;
                if (p < NPART && col4 < DE)
                    *(half4v*)(sEpvP[wv] + p*DE + col4) = pkcvt4(sumPv[v][t]);
            }
        }
    }
    __syncthreads();

    // ================= P2: cin gather into sCin (aliases sFrA) ==============
    for (int idx = threadIdx.x; idx < NPART*64; idx += 256) {
        int p = idx >> 6;
        int k = idx & 63;
        float v;
        if (k < PFEAT) {
            v = x[((size_t)bb*PFEAT + k)*NPART + p];
        } else if (k < PFEAT + DE) {
            v = sEpp[p*DE + (k - PFEAT)];
        } else if (k < PFEAT + 2*DE) {
            int c = k - PFEAT - DE;
            float s = 0.f;
#pragma unroll
            for (int w4 = 0; w4 < 4; ++w4)
                s += (float)sEpvP[w4][p*DE + c];
            v = s;
        } else {
            v = 0.f;
        }
        sCin[p*SR + k] = (_Float16)v;
    }
    __syncthreads();

    // ================= P3: object MLP (wave wv owns particle tile t=wv) =====
    {
        half8 bC[2];
        int p = 16*wv + ml;
        int sp = (p < NPART) ? p : 0;
#pragma unroll
        for (int kk = 0; kk < 2; ++kk)
            bC[kk] = *(const half8*)(sCin + sp*SR + kk*32 + q*8);

        f32x4 acc1[4];
#pragma unroll
        for (int u = 0; u < 4; ++u) {
            acc1[u] = bias4(fo_b1, u*16 + 4*q, HID - 3);
            acc1[u] = __builtin_amdgcn_mfma_f32_16x16x32_f16(fow1p[(u*2 + 0)*64 + lane], bC[0], acc1[u], 0, 0, 0);
            acc1[u] = __builtin_amdgcn_mfma_f32_16x16x32_f16(fow1p[(u*2 + 1)*64 + lane], bC[1], acc1[u], 0, 0, 0);
        }
        half4v a2[4];
#pragma unroll
        for (int u = 0; u < 4; ++u) a2[u] = relu4(pkcvt4(acc1[u]));

        f32x4 acc2[4];
#pragma unroll
        for (int u = 0; u < 4; ++u) {
            acc2[u] = bias4(fo_b2, u*16 + 4*q, HID - 3);
#pragma unroll
            for (int kt = 0; kt < 4; ++kt)
                acc2[u] = __builtin_amdgcn_mfma_f32_16x16x16f16(fow2p16[(u*4 + kt)*64 + lane], a2[kt], acc2[u], 0, 0, 0);
        }
        half4v a3[4];
#pragma unroll
        for (int u = 0; u < 4; ++u) a3[u] = relu4(pkcvt4(acc2[u]));

        f32x4 acc3[2];
#pragma unroll
        for (int v = 0; v < 2; ++v) {
            acc3[v] = bias4(fo_b3, v*16 + 4*q, DO - 3);
#pragma unroll
            for (int u = 0; u < 4; ++u)
                acc3[v] = __builtin_amdgcn_mfma_f32_16x16x16f16(fow3p16[(v*4 + u)*64 + lane], a3[u], acc3[v], 0, 0, 0);
        }
        // per-wave particle partial (16 particles of this tile)
#pragma unroll
        for (int v = 0; v < 2; ++v) {
            float s[4];
            bool ok = p < NPART;
#pragma unroll
            for (int i = 0; i < 4; ++i)
                s[i] = ok ? fmaxf(acc3[v][i], 0.f) : 0.f;
#pragma unroll
            for (int i = 0; i < 4; ++i) {
                s[i] += __shfl_xor(s[i], 1);
                s[i] += __shfl_xor(s[i], 2);
                s[i] += __shfl_xor(s[i], 4);
                s[i] += __shfl_xor(s[i], 8);
            }
            int col4 = v*16 + 4*q;
            if (ml == 0 && col4 < DO) {
                f32x4 o = {s[0], s[1], s[2], s[3]};
                *(f32x4*)(sDsum[wv] + col4) = o;
            }
        }
    }
    __syncthreads();

    // ================= fc head (wave 0) =====================================
    if (wv == 0) {
        float tot = 0.f;
        if (lane < DO) {
#pragma unroll
            for (int w4 = 0; w4 < 4; ++w4) tot += sDsum[w4][lane];
        }
        float p0 = (lane < DO) ? tot * fcw[lane*NCLS + 0] : 0.f;
        float p1 = (lane < DO) ? tot * fcw[lane*NCLS + 1] : 0.f;
#pragma unroll
        for (int d = 1; d <= 16; d <<= 1) {
            p0 += __shfl_xor(p0, d);
            p1 += __shfl_xor(p1, d);
        }
        if (lane == 0) {
            out[bb*NCLS + 0] = p0 + fcb[0];
            out[bb*NCLS + 1] = p1 + fcb[1];
        }
    }
}

// ---------------------------------------------------------------------------
extern "C" void kernel_launch(void* const* d_in, const int* in_sizes, int n_in,
                              void* d_out, int out_size, void* d_ws, size_t ws_size,
                              hipStream_t stream)
{
    const float* x     = (const float*)d_in[0];
    const float* y     = (const float*)d_in[1];
    const float* fr_w1 = (const float*)d_in[2];
    const float* fr_b1 = (const float*)d_in[3];
    const float* fr_w2 = (const float*)d_in[4];
    const float* fr_b2 = (const float*)d_in[5];
    const float* fr_w3 = (const float*)d_in[6];
    const float* fr_b3 = (const float*)d_in[7];
    const float* pv_w1 = (const float*)d_in[8];
    const float* pv_b1 = (const float*)d_in[9];
    const float* pv_w2 = (const float*)d_in[10];
    const float* pv_b2 = (const float*)d_in[11];
    const float* pv_w3 = (const float*)d_in[12];
    const float* pv_b3 = (const float*)d_in[13];
    const float* fo_w1 = (const float*)d_in[14];
    const float* fo_b1 = (const float*)d_in[15];
    const float* fo_w2 = (const float*)d_in[16];
    const float* fo_b2 = (const float*)d_in[17];
    const float* fo_w3 = (const float*)d_in[18];
    const float* fo_b3 = (const float*)d_in[19];
    const float* fc_w  = (const float*)d_in[20];
    const float* fc_b  = (const float*)d_in[21];
    float* out = (float*)d_out;

    char* wsb = (char*)d_ws;
    size_t off = 0;
    auto alloc = [&](size_t bytes) { char* p = wsb + off; off += (bytes + 255) & ~(size_t)255; return p; };

    _Float16* frW2p   = (_Float16*)alloc(4096*2);
    _Float16* frW3p16 = (_Float16*)alloc(2048*2);
    _Float16* pvW2p   = (_Float16*)alloc(4096*2);
    _Float16* pvW3p16 = (_Float16*)alloc(2048*2);
    _Float16* foW1p   = (_Float16*)alloc(4096*2);
    _Float16* foW2p16 = (_Float16*)alloc(4096*2);
    _Float16* foW3p16 = (_Float16*)alloc(2048*2);

    pack_kernel<<<16, 256, 0, stream>>>(
        fr_w2, fr_w3, pv_w2, pv_w3, fo_w1, fo_w2, fo_w3,
        frW2p, frW3p16, pvW2p, pvW3p16, foW1p, foW2p16, foW3p16);

    fused_kernel<<<BATCH, 256, 0, stream>>>(
        x, y, fr_w1, fr_b1, fr_b2, fr_b3,
        pv_w1, pv_b1, pv_b2, pv_b3,
        fo_b1, fo_b2, fo_b3, fc_w, fc_b,
        (const half8*)frW2p, (const half4v*)frW3p16,
        (const half8*)pvW2p, (const half4v*)pvW3p16,
        (const half8*)foW1p, (const half4v*)foW2p16, (const half4v*)foW3p16,
        out);
}